// Round 13
// baseline (74.673 us; speedup 1.0000x reference)
//
#include <hip/hip_runtime.h>
#include <math.h>

// ListNet segment-softmax CE — ROUND 13: named-probe measurement round.
// Pipeline = r5 champion (23.2us) exactly, but main body reps x4 inside
// mp_probe4 and finalize body reps x8 inside fin_probe8 (both idempotent,
// per-rep state reset, asm memory barrier defeats load hoisting). This
// surfaces the main pass in the top-5 window (> ~41us fills) WITH its own
// counters, and recovers finalize time by arithmetic:
//   T13 = M4 + F8 + gaps;  m_hot ~ M4/4;  f ~ (T13 - M4 - 3)/8.
// Output remains exact (absmax 0.0 expected, as r2-r12).

#define TPB 256
#define K 16
#define CHUNK (TPB * K)   // 4096 items per block
#define SLOTS 768
#define MREPS 4
#define FREPS 8

__global__ __launch_bounds__(TPB) void mp_probe4(
        const float* __restrict__ scores, const float* __restrict__ labels,
        const int* __restrict__ widx,
        int* __restrict__ rec_week, float* __restrict__ rec_el,
        float* __restrict__ rec_es, float* __restrict__ rec_tl,
        int* __restrict__ rec_cnt,
        float* __restrict__ part_loss, int* __restrict__ part_nv) {
    __shared__ float lel[SLOTS], les[SLOTS], ltl[SLOTS];
    __shared__ int   lcnt[SLOTS];
    __shared__ float ra4[4];
    __shared__ int   rn4[4];
    const int tid = threadIdx.x;
    const int lane = tid & 63, wv = tid >> 6;
    const int base = blockIdx.x * CHUNK;
    const int w0 = widx[base];
    const int wl = widx[base + CHUNK - 1];
    const int span = wl - w0;

    #pragma unroll 1
    for (int rep = 0; rep < MREPS; ++rep) {
        asm volatile("" ::: "memory");   // force re-load / no cross-rep folding
        for (int s = tid; s <= span; s += TPB) {
            lel[s] = 0.f; les[s] = 0.f; ltl[s] = 0.f; lcnt[s] = 0;
        }
        __syncthreads();

        const int t0 = base + tid * K;
        const int4   wA = *reinterpret_cast<const int4*>(widx + t0);
        const int4   wB = *reinterpret_cast<const int4*>(widx + t0 + 4);
        const int4   wC = *reinterpret_cast<const int4*>(widx + t0 + 8);
        const int4   wD = *reinterpret_cast<const int4*>(widx + t0 + 12);
        const float4 lA = *reinterpret_cast<const float4*>(labels + t0);
        const float4 lB = *reinterpret_cast<const float4*>(labels + t0 + 4);
        const float4 lC = *reinterpret_cast<const float4*>(labels + t0 + 8);
        const float4 lD = *reinterpret_cast<const float4*>(labels + t0 + 12);
        const float4 sA = *reinterpret_cast<const float4*>(scores + t0);
        const float4 sB = *reinterpret_cast<const float4*>(scores + t0 + 4);
        const float4 sC = *reinterpret_cast<const float4*>(scores + t0 + 8);
        const float4 sD = *reinterpret_cast<const float4*>(scores + t0 + 12);

        float loss = 0.f; int nv = 0;
        int cw; float ra, rb, rt; int rc;
        bool head_saved = false;
        int hs = 0; float ha = 0.f, hb = 0.f, ht = 0.f; int hc = 0;
        {
            const float el = __expf(lA.x), es = __expf(sA.x);
            cw = wA.x; ra = el; rb = es; rt = el * sA.x; rc = 1;
        }
#define ITEM(wv_, lv_, sv_)                                                    \
    {                                                                          \
        const float el = __expf(lv_), es = __expf(sv_);                        \
        if ((wv_) == cw) { ra += el; rb += es; rt += el * (sv_); ++rc; }       \
        else {                                                                 \
            if (!head_saved) {                                                 \
                hs = cw - w0; ha = ra; hb = rb; ht = rt; hc = rc;              \
                head_saved = true;                                             \
            } else if (rc >= 2) {                                              \
                loss += rt / ra - __logf(rb); ++nv;                            \
            }                                                                  \
            cw = (wv_); ra = el; rb = es; rt = el * (sv_); rc = 1;             \
        }                                                                      \
    }
        ITEM(wA.y, lA.y, sA.y) ITEM(wA.z, lA.z, sA.z) ITEM(wA.w, lA.w, sA.w)
        ITEM(wB.x, lB.x, sB.x) ITEM(wB.y, lB.y, sB.y) ITEM(wB.z, lB.z, sB.z)
        ITEM(wB.w, lB.w, sB.w)
        ITEM(wC.x, lC.x, sC.x) ITEM(wC.y, lC.y, sC.y) ITEM(wC.z, lC.z, sC.z)
        ITEM(wC.w, lC.w, sC.w)
        ITEM(wD.x, lD.x, sD.x) ITEM(wD.y, lD.y, sD.y) ITEM(wD.z, lD.z, sD.z)
        ITEM(wD.w, lD.w, sD.w)
#undef ITEM
        if (head_saved) {
            atomicAdd(&lel[hs], ha); atomicAdd(&les[hs], hb);
            atomicAdd(&ltl[hs], ht); atomicAdd(&lcnt[hs], hc);
        }
        const int ts = cw - w0;
        atomicAdd(&lel[ts], ra); atomicAdd(&les[ts], rb);
        atomicAdd(&ltl[ts], rt); atomicAdd(&lcnt[ts], rc);
        __syncthreads();

        for (int s = 1 + tid; s < span; s += TPB) {
            const int c = lcnt[s];
            if (c >= 2) { loss += ltl[s] / lel[s] - __logf(les[s]); ++nv; }
        }
        #pragma unroll
        for (int off = 32; off; off >>= 1) {
            loss += __shfl_down(loss, off);
            nv   += __shfl_down(nv, off);
        }
        if (lane == 0) { ra4[wv] = loss; rn4[wv] = nv; }
        __syncthreads();
        if (tid == 0) {
            part_loss[blockIdx.x] = ra4[0] + ra4[1] + ra4[2] + ra4[3];
            part_nv[blockIdx.x]   = rn4[0] + rn4[1] + rn4[2] + rn4[3];
            const int b2 = blockIdx.x * 2;
            rec_week[b2] = w0;
            rec_el[b2] = lel[0]; rec_es[b2] = les[0];
            rec_tl[b2] = ltl[0]; rec_cnt[b2] = lcnt[0];
            rec_week[b2 + 1] = wl;
            if (span > 0) {
                rec_el[b2 + 1] = lel[span]; rec_es[b2 + 1] = les[span];
                rec_tl[b2 + 1] = ltl[span]; rec_cnt[b2 + 1] = lcnt[span];
            } else {
                rec_el[b2 + 1] = 0.f; rec_es[b2 + 1] = 0.f;
                rec_tl[b2 + 1] = 0.f; rec_cnt[b2 + 1] = 0;
            }
        }
        __syncthreads();   // slots/ra4 free before next rep re-init
    }
}

__global__ __launch_bounds__(1024) void fin_probe8(
        const int* __restrict__ rec_week, const float* __restrict__ rec_el,
        const float* __restrict__ rec_es, const float* __restrict__ rec_tl,
        const int* __restrict__ rec_cnt,
        const float* __restrict__ part_loss, const int* __restrict__ part_nv,
        int nrec, int nb, float* __restrict__ out) {
    __shared__ float ra[16];
    __shared__ int   rn[16];
    const int tid = threadIdx.x;
    const int lane = tid & 63, wv = tid >> 6;

    #pragma unroll 1
    for (int rep = 0; rep < FREPS; ++rep) {
        asm volatile("" ::: "memory");
        float loss = 0.f; int nv = 0;
        for (int j = tid; j < nrec; j += 1024) {
            const int w = rec_week[j];
            if (j > 0 && rec_week[j - 1] == w) continue;  // not a run head
            float a = rec_el[j], b = rec_es[j], t = rec_tl[j];
            int c = rec_cnt[j];
            for (int k = j + 1; k < nrec && rec_week[k] == w; ++k) {
                a += rec_el[k]; b += rec_es[k]; t += rec_tl[k]; c += rec_cnt[k];
            }
            if (c >= 2) { loss += t / a - __logf(b); ++nv; }
        }
        for (int j = tid; j < nb; j += 1024) {
            loss += part_loss[j]; nv += part_nv[j];
        }
        #pragma unroll
        for (int off = 32; off; off >>= 1) {
            loss += __shfl_down(loss, off);
            nv   += __shfl_down(nv, off);
        }
        if (lane == 0) { ra[wv] = loss; rn[wv] = nv; }
        __syncthreads();
        if (tid == 0) {
            float tl = 0.f; int tn = 0;
            for (int k = 0; k < 16; ++k) { tl += ra[k]; tn += rn[k]; }
            out[0] = (tn > 0) ? (-tl / (float)tn) : 0.f;
        }
        __syncthreads();   // ra/rn free before next rep
    }
}

extern "C" void kernel_launch(void* const* d_in, const int* in_sizes, int n_in,
                              void* d_out, int out_size, void* d_ws, size_t ws_size,
                              hipStream_t stream) {
    const float* scores = (const float*)d_in[0];
    const float* labels = (const float*)d_in[1];
    const int*   widx   = (const int*)d_in[2];
    const int n  = in_sizes[0];
    const int nb = n / CHUNK;      // 1024
    const int nrec = nb * 2;

    char* ws = (char*)d_ws;
    size_t off = 0;
    int*   rec_week = (int*)  (ws + off); off += (size_t)nrec * 4;
    float* rec_el   = (float*)(ws + off); off += (size_t)nrec * 4;
    float* rec_es   = (float*)(ws + off); off += (size_t)nrec * 4;
    float* rec_tl   = (float*)(ws + off); off += (size_t)nrec * 4;
    int*   rec_cnt  = (int*)  (ws + off); off += (size_t)nrec * 4;
    float* part_loss= (float*)(ws + off); off += (size_t)nb * 4;
    int*   part_nv  = (int*)  (ws + off);

    float* out = (float*)d_out;

    mp_probe4<<<nb, TPB, 0, stream>>>(scores, labels, widx,
                                      rec_week, rec_el, rec_es, rec_tl, rec_cnt,
                                      part_loss, part_nv);
    fin_probe8<<<1, 1024, 0, stream>>>(rec_week, rec_el, rec_es, rec_tl, rec_cnt,
                                       part_loss, part_nv, nrec, nb, out);
}